// Round 1
// baseline (60.158 us; speedup 1.0000x reference)
//
#include <hip/hip_runtime.h>

// Problem constants (derived from reference: B=4096, N=4097)
constexpr int NPTS = 4097;   // points per row
constexpr int M    = 4096;   // = NPTS-1, elements of z / x_sl per row
constexpr int TPB  = 256;    // threads per block (4 waves)
constexpr int EPT  = 16;     // elements per thread (TPB*EPT == M)

__global__ __launch_bounds__(TPB)
void vp_kernel(const float* __restrict__ x, const float* __restrict__ t,
               const float* __restrict__ params, float* __restrict__ out, int B)
{
    const int b    = blockIdx.x;
    const int tid  = threadIdx.x;
    const int lane = tid & 63;
    const int wid  = tid >> 6;
    const int m0   = tid * EPT;

    const float r  = params[0];
    const float ny = params[1];

    const float* __restrict__ xrow = x + (size_t)b * NPTS;

    // ---- load this thread's 17 x-values and 17 t-values (registers) ----
    float xv[EPT + 1], tv[EPT + 1];
#pragma unroll
    for (int k = 0; k <= EPT; ++k) {
        xv[k] = xrow[m0 + k];
        tv[k] = t[m0 + k];          // t is 16KB, L2-hot across all blocks
    }

    // ---- local inclusive scan of trapezoid increments ----
    float zl[EPT];
    float run = 0.f;
#pragma unroll
    for (int k = 0; k < EPT; ++k) {
        run += 0.5f * (tv[k + 1] - tv[k]) * (xv[k] + xv[k + 1]);
        zl[k] = run;
    }

    // ---- wave inclusive scan of thread totals (64 lanes) ----
    float v = run;
#pragma unroll
    for (int d = 1; d < 64; d <<= 1) {
        float u = __shfl_up(v, d, 64);
        if (lane >= d) v += u;
    }

    __shared__ float  wtot[TPB / 64];
    __shared__ double wred[TPB / 64][6];
    __shared__ float  cbc[2];

    if (lane == 63) wtot[wid] = v;
    __syncthreads();
    float woff = 0.f;
#pragma unroll
    for (int w = 0; w < TPB / 64; ++w)
        if (w < wid) woff += wtot[w];
    // exclusive prefix for this thread, with ny folded in
    const float base = ny + woff + (v - run);

    // ---- z, w = z^r, and the 5 Gram/projection sums (double accum) ----
    double szz = 0, szw = 0, sww = 0, sxz = 0, sxw = 0;
    float wv[EPT];
#pragma unroll
    for (int k = 0; k < EPT; ++k) {
        float z = base + zl[k];
        float w = (r == 0.5f) ? sqrtf(z) : powf(z, r);
        zl[k] = z;                       // zl now holds z
        wv[k] = w;
        float xs = xv[k + 1];
        szz += (double)z  * (double)z;
        szw += (double)z  * (double)w;
        sww += (double)w  * (double)w;
        sxz += (double)xs * (double)z;
        sxw += (double)xs * (double)w;
    }
#pragma unroll
    for (int d = 32; d > 0; d >>= 1) {
        szz += __shfl_down(szz, d, 64);
        szw += __shfl_down(szw, d, 64);
        sww += __shfl_down(sww, d, 64);
        sxz += __shfl_down(sxz, d, 64);
        sxw += __shfl_down(sxw, d, 64);
    }
    if (lane == 0) {
        wred[wid][0] = szz; wred[wid][1] = szw; wred[wid][2] = sww;
        wred[wid][3] = sxz; wred[wid][4] = sxw;
    }
    __syncthreads();

    // ---- 2x2 normal-equations solve (coeffs = b @ G^-1), double ----
    if (tid == 0) {
        double a0 = 0, a1 = 0, a2 = 0, a3 = 0, a4 = 0;
        for (int w = 0; w < TPB / 64; ++w) {
            a0 += wred[w][0]; a1 += wred[w][1]; a2 += wred[w][2];
            a3 += wred[w][3]; a4 += wred[w][4];
        }
        double det = a0 * a2 - a1 * a1;
        double inv = 1.0 / det;
        double c0 = (a3 * a2 - a4 * a1) * inv;
        double c1 = (a4 * a0 - a3 * a1) * inv;
        out[(size_t)b * 2 + 0] = (float)c0;
        out[(size_t)b * 2 + 1] = (float)c1;
        cbc[0] = (float)c0; cbc[1] = (float)c1;
    }
    __syncthreads();
    const float c0 = cbc[0], c1 = cbc[1];

    // ---- x_hat, res, r2; vectorized float4 stores (16B aligned) ----
    float* __restrict__ xhat = out + (size_t)B * 2 + (size_t)b * M;
    float* __restrict__ res  = out + (size_t)B * 2 + (size_t)B * M + (size_t)b * M;

    double r2 = 0;
#pragma unroll
    for (int q = 0; q < EPT / 4; ++q) {
        float h0 = c0 * zl[4 * q + 0] + c1 * wv[4 * q + 0];
        float h1 = c0 * zl[4 * q + 1] + c1 * wv[4 * q + 1];
        float h2 = c0 * zl[4 * q + 2] + c1 * wv[4 * q + 2];
        float h3 = c0 * zl[4 * q + 3] + c1 * wv[4 * q + 3];
        float e0 = xv[4 * q + 1] - h0;
        float e1 = xv[4 * q + 2] - h1;
        float e2 = xv[4 * q + 3] - h2;
        float e3 = xv[4 * q + 4] - h3;
        *reinterpret_cast<float4*>(xhat + m0 + 4 * q) = make_float4(h0, h1, h2, h3);
        *reinterpret_cast<float4*>(res  + m0 + 4 * q) = make_float4(e0, e1, e2, e3);
        r2 += (double)e0 * e0 + (double)e1 * e1 + (double)e2 * e2 + (double)e3 * e3;
    }
#pragma unroll
    for (int d = 32; d > 0; d >>= 1) r2 += __shfl_down(r2, d, 64);
    if (lane == 0) wred[wid][5] = r2;
    __syncthreads();
    if (tid == 0) {
        double s = 0;
        for (int w = 0; w < TPB / 64; ++w) s += wred[w][5];
        out[(size_t)B * 2 + 2 * (size_t)B * M + b] = (float)s;
    }
}

extern "C" void kernel_launch(void* const* d_in, const int* in_sizes, int n_in,
                              void* d_out, int out_size, void* d_ws, size_t ws_size,
                              hipStream_t stream) {
    const float* x = (const float*)d_in[0];
    const float* t = (const float*)d_in[1];
    const float* p = (const float*)d_in[2];
    float* out     = (float*)d_out;
    const int B    = in_sizes[0] / NPTS;   // 4096

    vp_kernel<<<dim3(B), dim3(TPB), 0, stream>>>(x, t, p, out, B);
}

// Round 2
// 42.607 us; speedup vs baseline: 1.4119x; 1.4119x over previous
//
#include <hip/hip_runtime.h>

// B=4096 rows, NPTS=4097 points, M=4096 outputs per row.
constexpr int NPTS = 4097;
constexpr int M    = 4096;
constexpr int TPB  = 256;   // 4 waves
constexpr int NJ   = 4;     // groups of 4 per thread; NJ*TPB*4 == M
// thread owns elements e(j) = j*1024 + tid*4 .. +3  (lane-contiguous float4)

__global__ __launch_bounds__(TPB)
void vp_kernel(const float* __restrict__ x, const float* __restrict__ t,
               const float* __restrict__ params, float* __restrict__ out, int B)
{
    const int b    = blockIdx.x;
    const int tid  = threadIdx.x;
    const int lane = tid & 63;
    const int wid  = tid >> 6;

    const float r  = params[0];
    const float ny = params[1];

    const float* __restrict__ xrow = x + (size_t)b * NPTS;

    float xs[NJ][4];   // x_sl = x[m+1] for this thread's elements
    float zl[NJ][4];   // local inclusive scan (later: z)
    float gs[NJ];      // group sums (kept), sc[j] = wave-scanned

    // ---- coalesced loads + local 4-element trapezoid scans ----
#pragma unroll
    for (int j = 0; j < NJ; ++j) {
        const int e = j * 1024 + tid * 4;
        // x row is misaligned for b%4!=0 -> coalesced scalar loads (safe)
        float x0 = xrow[e],     x1 = xrow[e + 1], x2 = xrow[e + 2];
        float x3 = xrow[e + 3], x4 = xrow[e + 4];
        float4 tq = *reinterpret_cast<const float4*>(t + e);   // t base aligned
        float  tn = t[e + 4];
        float i0 = 0.5f * (tq.y - tq.x) * (x0 + x1);
        float i1 = 0.5f * (tq.z - tq.y) * (x1 + x2);
        float i2 = 0.5f * (tq.w - tq.z) * (x2 + x3);
        float i3 = 0.5f * (tn   - tq.w) * (x3 + x4);
        zl[j][0] = i0;
        zl[j][1] = i0 + i1;
        zl[j][2] = i0 + i1 + i2;
        zl[j][3] = i0 + i1 + i2 + i3;
        gs[j] = zl[j][3];
        xs[j][0] = x1; xs[j][1] = x2; xs[j][2] = x3; xs[j][3] = x4;
    }

    // ---- 4 simultaneous wave inclusive scans of group sums ----
    float sc0 = gs[0], sc1 = gs[1], sc2 = gs[2], sc3 = gs[3];
#pragma unroll
    for (int d = 1; d < 64; d <<= 1) {
        float u0 = __shfl_up(sc0, d, 64);
        float u1 = __shfl_up(sc1, d, 64);
        float u2 = __shfl_up(sc2, d, 64);
        float u3 = __shfl_up(sc3, d, 64);
        if (lane >= d) { sc0 += u0; sc1 += u1; sc2 += u2; sc3 += u3; }
    }

    __shared__ float  wt[TPB / 64][NJ];
    __shared__ double wred[TPB / 64][6];
    __shared__ float  cbc[2];

    if (lane == 63) {
        wt[wid][0] = sc0; wt[wid][1] = sc1; wt[wid][2] = sc2; wt[wid][3] = sc3;
    }
    __syncthreads();

    float woff[NJ] = {0, 0, 0, 0};
    float Tj[NJ]   = {0, 0, 0, 0};
#pragma unroll
    for (int w = 0; w < TPB / 64; ++w) {
#pragma unroll
        for (int j = 0; j < NJ; ++j) {
            float v = wt[w][j];
            Tj[j] += v;
            if (w < wid) woff[j] += v;
        }
    }
    // exclusive prefix per group, memory order = j-major, tid-minor
    float zbase[NJ];
    float jacc = 0.f;
    float scv[NJ] = {sc0, sc1, sc2, sc3};
#pragma unroll
    for (int j = 0; j < NJ; ++j) {
        zbase[j] = ny + jacc + woff[j] + (scv[j] - gs[j]);
        jacc += Tj[j];
    }

    // ---- z, w=z^r, Gram/projection sums (double accumulation) ----
    double szz = 0, szw = 0, sww = 0, sxz = 0, sxw = 0;
#pragma unroll
    for (int j = 0; j < NJ; ++j) {
#pragma unroll
        for (int i = 0; i < 4; ++i) {
            float z = zbase[j] + zl[j][i];
            zl[j][i] = z;
            float w = (r == 0.5f) ? sqrtf(z) : powf(z, r);
            float xv = xs[j][i];
            szz += (double)z  * (double)z;
            szw += (double)z  * (double)w;
            sww += (double)w  * (double)w;
            sxz += (double)xv * (double)z;
            sxw += (double)xv * (double)w;
        }
    }
#pragma unroll
    for (int d = 32; d > 0; d >>= 1) {
        szz += __shfl_down(szz, d, 64);
        szw += __shfl_down(szw, d, 64);
        sww += __shfl_down(sww, d, 64);
        sxz += __shfl_down(sxz, d, 64);
        sxw += __shfl_down(sxw, d, 64);
    }
    if (lane == 0) {
        wred[wid][0] = szz; wred[wid][1] = szw; wred[wid][2] = sww;
        wred[wid][3] = sxz; wred[wid][4] = sxw;
    }
    __syncthreads();

    // ---- 2x2 normal-equations solve, double ----
    if (tid == 0) {
        double a0 = 0, a1 = 0, a2 = 0, a3 = 0, a4 = 0;
        for (int w = 0; w < TPB / 64; ++w) {
            a0 += wred[w][0]; a1 += wred[w][1]; a2 += wred[w][2];
            a3 += wred[w][3]; a4 += wred[w][4];
        }
        double det = a0 * a2 - a1 * a1;
        double inv = 1.0 / det;
        double c0 = (a3 * a2 - a4 * a1) * inv;
        double c1 = (a4 * a0 - a3 * a1) * inv;
        out[(size_t)b * 2 + 0] = (float)c0;
        out[(size_t)b * 2 + 1] = (float)c1;
        cbc[0] = (float)c0; cbc[1] = (float)c1;
    }
    __syncthreads();
    const float c0 = cbc[0], c1 = cbc[1];

    // ---- x_hat, res (coalesced float4 stores), r2 ----
    float* __restrict__ xhat = out + (size_t)B * 2 + (size_t)b * M;
    float* __restrict__ res  = xhat + (size_t)B * M;

    double r2 = 0;
#pragma unroll
    for (int j = 0; j < NJ; ++j) {
        const int e = j * 1024 + tid * 4;
        float h[4], ev[4];
#pragma unroll
        for (int i = 0; i < 4; ++i) {
            float z = zl[j][i];
            float w = (r == 0.5f) ? sqrtf(z) : powf(z, r);
            h[i]  = c0 * z + c1 * w;
            ev[i] = xs[j][i] - h[i];
            r2 += (double)ev[i] * (double)ev[i];
        }
        *reinterpret_cast<float4*>(xhat + e) = make_float4(h[0], h[1], h[2], h[3]);
        *reinterpret_cast<float4*>(res  + e) = make_float4(ev[0], ev[1], ev[2], ev[3]);
    }
#pragma unroll
    for (int d = 32; d > 0; d >>= 1) r2 += __shfl_down(r2, d, 64);
    if (lane == 0) wred[wid][5] = r2;
    __syncthreads();
    if (tid == 0) {
        double s = 0;
        for (int w = 0; w < TPB / 64; ++w) s += wred[w][5];
        out[(size_t)B * 2 + 2 * (size_t)B * M + b] = (float)s;
    }
}

extern "C" void kernel_launch(void* const* d_in, const int* in_sizes, int n_in,
                              void* d_out, int out_size, void* d_ws, size_t ws_size,
                              hipStream_t stream) {
    const float* x = (const float*)d_in[0];
    const float* t = (const float*)d_in[1];
    const float* p = (const float*)d_in[2];
    float* out     = (float*)d_out;
    const int B    = in_sizes[0] / NPTS;   // 4096

    vp_kernel<<<dim3(B), dim3(TPB), 0, stream>>>(x, t, p, out, B);
}